// Round 9
// baseline (228.423 us; speedup 1.0000x reference)
//
#include <hip/hip_runtime.h>
#include <hip/hip_bf16.h>
#include <math.h>

using bf16 = __hip_bfloat16;

typedef __attribute__((ext_vector_type(4))) float fv4;
typedef __attribute__((ext_vector_type(4))) short sh4;
typedef __attribute__((ext_vector_type(8))) short sh8;
typedef __attribute__((ext_vector_type(4))) float f4acc;

#define T_TOK 2048
#define HD    1024
#define NE    16
#define KD    1024
#define NPAIR 8192

// ---- workspace layout (bytes); peak ~73.5 MB (proven ws >= 75.6 MB in R1-R4) ----
static constexpr size_t OFF_XB   = 0;          // bf16 xb  [2048][1024]  4 MiB
static constexpr size_t OFF_GUB  = 4194304;    // bf16 gu  [2048][2048]  8 MiB
static constexpr size_t OFF_ACT  = 12582912;   // bf16 act [2048][1024]  4 MiB
static constexpr size_t OFF_H1   = 16777216;   // bf16 h1  [8192][1024] 16 MiB
static constexpr size_t OFF_W1B  = 33554432;   // bf16 w1b [16<<20] 32 MiB; aliased w2b after K2
static constexpr size_t OFF_SGUB = 67108864;   // bf16 sgu [2048][1024] 4 MiB
static constexpr size_t OFF_SDNB = 71303168;   // bf16 sdn [1024][1024] 2 MiB
static constexpr size_t OFF_TOPI = 73400320;   // int  [8192]
static constexpr size_t OFF_TOPV = 73433088;   // f32  [8192]
static constexpr size_t OFF_PTOK = 73465856;   // int  [8192]
static constexpr size_t OFF_PWT  = 73498624;   // f32  [8192]
static constexpr size_t OFF_OFFS = 73531392;   // int  [17]

__device__ __forceinline__ short f2bf(float f) {
  __hip_bfloat16 h = __float2bfloat16(f);
  union { __hip_bfloat16 b; short s; } u; u.b = h; return u.s;
}
__device__ __forceinline__ float bf2f(short s) {
  union { unsigned u; float f; } c; c.u = ((unsigned)(unsigned short)s) << 16; return c.f;
}
__device__ __forceinline__ void async16(const void* g, void* l) {
  __builtin_amdgcn_global_load_lds(
      (const __attribute__((address_space(1))) void*)g,
      (__attribute__((address_space(3))) void*)l, 16, 0, 0);
}

// ---------- cast1: w1, sgu, sdn (fp32 -> bf16), one fv4/thread ----------
__global__ __launch_bounds__(256) void cast1_kernel(const float* __restrict__ w1,
                                                    const float* __restrict__ sgu,
                                                    const float* __restrict__ sdn,
                                                    short* __restrict__ w1b,
                                                    short* __restrict__ sgub,
                                                    short* __restrict__ sdnb) {
  int bid = blockIdx.x;
  const float* src; short* dst; int idx;
  if (bid < 16384)      { src = w1;  dst = w1b;  idx = bid * 256 + threadIdx.x; }
  else if (bid < 18432) { src = sgu; dst = sgub; idx = (bid - 16384) * 256 + threadIdx.x; }
  else                  { src = sdn; dst = sdnb; idx = (bid - 18432) * 256 + threadIdx.x; }
  fv4 v = ((const fv4*)src)[idx];
  sh4 o; o[0]=f2bf(v[0]); o[1]=f2bf(v[1]); o[2]=f2bf(v[2]); o[3]=f2bf(v[3]);
  ((sh4*)dst)[idx] = o;
}

// ---------- router: no atomics; gw in LDS; also emits xb (bf16 cast of x) ----------
__global__ __launch_bounds__(256) void router_kernel(const float* __restrict__ x,
                                                     const float* __restrict__ gw,
                                                     int* __restrict__ topi,
                                                     float* __restrict__ topv,
                                                     short* __restrict__ xb) {
  __shared__ float gsh[NE * HD];  // 64 KiB
  const int tid = threadIdx.x;
  const int wave = tid >> 6;
  const int lane = tid & 63;
  const int t = blockIdx.x * 4 + wave;

#pragma unroll
  for (int r = 0; r < 16; ++r) {
    int idx = r * 256 + tid;
    ((fv4*)gsh)[idx] = ((const fv4*)gw)[idx];
  }

  const float* xr = x + (size_t)t * HD;
  fv4 xa[4];
#pragma unroll
  for (int q = 0; q < 4; ++q) xa[q] = *(const fv4*)(xr + q * 256 + lane * 4);

  // by-product: write bf16 x row
#pragma unroll
  for (int q = 0; q < 4; ++q) {
    sh4 o; o[0]=f2bf(xa[q][0]); o[1]=f2bf(xa[q][1]); o[2]=f2bf(xa[q][2]); o[3]=f2bf(xa[q][3]);
    *(sh4*)(xb + (size_t)t * HD + q * 256 + lane * 4) = o;
  }

  __syncthreads();

  float p[NE];
#pragma unroll
  for (int e = 0; e < NE; ++e) {
    const float* g = gsh + e * HD;
    float a = 0.f;
#pragma unroll
    for (int q = 0; q < 4; ++q) {
      fv4 gv = *(const fv4*)(g + q * 256 + lane * 4);
      a += xa[q][0] * gv[0] + xa[q][1] * gv[1] + xa[q][2] * gv[2] + xa[q][3] * gv[3];
    }
    p[e] = a;
  }
#pragma unroll
  for (int off = 1; off < 64; off <<= 1) {
#pragma unroll
    for (int e = 0; e < NE; ++e) p[e] += __shfl_xor(p[e], off);
  }

  int sel_i[4]; float sel_v[4];
#pragma unroll
  for (int k = 0; k < 4; ++k) {
    float best = p[0]; int bi = 0;
#pragma unroll
    for (int e = 1; e < NE; ++e) {
      bool c = p[e] > best;
      best = c ? p[e] : best;
      bi   = c ? e : bi;
    }
    sel_i[k] = bi; sel_v[k] = best;
#pragma unroll
    for (int e = 0; e < NE; ++e) p[e] = (e == bi) ? -3.4e38f : p[e];
  }
  float m = sel_v[0];
  float e0 = expf(sel_v[0] - m), e1 = expf(sel_v[1] - m);
  float e2 = expf(sel_v[2] - m), e3 = expf(sel_v[3] - m);
  float inv = 1.f / (e0 + e1 + e2 + e3);

  if (lane == 0) {
    topi[t * 4 + 0] = sel_i[0]; topv[t * 4 + 0] = e0 * inv;
    topi[t * 4 + 1] = sel_i[1]; topv[t * 4 + 1] = e1 * inv;
    topi[t * 4 + 2] = sel_i[2]; topv[t * 4 + 2] = e2 * inv;
    topi[t * 4 + 3] = sel_i[3]; topv[t * 4 + 3] = e3 * inv;
  }
}

// ---------- route build: ballot-based; emits pair_token + pair_weight ----------
__global__ __launch_bounds__(1024) void route_build_kernel(const int* __restrict__ topi,
                                                           const float* __restrict__ topv,
                                                           int* __restrict__ offsets,
                                                           int* __restrict__ pair_token,
                                                           float* __restrict__ pair_weight) {
  __shared__ int tsh[NPAIR];
  __shared__ int cnt_sh[NE];
  __shared__ int off_sh[NE + 1];
  const int tid = threadIdx.x;
  const int wave = tid >> 6;
  const int lane = tid & 63;

#pragma unroll
  for (int r = 0; r < NPAIR / 1024; ++r) tsh[r * 1024 + tid] = topi[r * 1024 + tid];
  __syncthreads();

  const int e = wave;
  int cnt = 0;
  for (int c = 0; c < NPAIR; c += 64) {
    unsigned long long msk = __ballot(tsh[c + lane] == e);
    cnt += __popcll(msk);
  }
  if (lane == 0) cnt_sh[e] = cnt;
  __syncthreads();
  if (tid == 0) {
    int acc = 0;
    for (int i = 0; i < NE; ++i) { off_sh[i] = acc; acc += cnt_sh[i]; }
    off_sh[NE] = acc;
  }
  __syncthreads();
  if (tid <= NE) offsets[tid] = off_sh[tid];

  int base = off_sh[e];
  for (int c = 0; c < NPAIR; c += 64) {
    bool match = (tsh[c + lane] == e);
    unsigned long long msk = __ballot(match);
    unsigned long long lt = (lane == 0) ? 0ull : ((~0ull) >> (64 - lane));
    int pre = __popcll(msk & lt);
    if (match) {
      int slot = base + pre;
      pair_token[slot] = (c + lane) >> 2;
      pair_weight[slot] = topv[c + lane];
    }
    base += __popcll(msk);
  }
}

// ---------- act + w2 cast ----------
__global__ __launch_bounds__(256) void act_w2_kernel(const float* __restrict__ w2,
                                                     short* __restrict__ w2b,
                                                     const short* __restrict__ gub,
                                                     short* __restrict__ act) {
  int bid = blockIdx.x;
  if (bid < 16384) {
    int idx = bid * 256 + threadIdx.x;
    fv4 v = ((const fv4*)w2)[idx];
    sh4 o; o[0]=f2bf(v[0]); o[1]=f2bf(v[1]); o[2]=f2bf(v[2]); o[3]=f2bf(v[3]);
    ((sh4*)w2b)[idx] = o;
  } else {
    int i = (bid - 16384) * 256 + threadIdx.x;
    int t = i >> 8, g = i & 255;
    sh4 gs = *(const sh4*)(gub + (size_t)t * 2048 + g * 4);
    sh4 us = *(const sh4*)(gub + (size_t)t * 2048 + 1024 + g * 4);
    sh4 o;
#pragma unroll
    for (int q = 0; q < 4; ++q) {
      float gg = bf2f(gs[q]);
      float s = gg / (1.f + expf(-gg)) * bf2f(us[q]);
      o[q] = f2bf(s);
    }
    *(sh4*)(act + (size_t)t * 1024 + g * 4) = o;
  }
}

// ---------- 256x256 BK=64 8-wave GEMM, minimum 2-phase template ----------
// Both A and B bf16, staged via global_load_lds. One barrier per K-step.
// Wave (wm=wave>>2, wn=wave&3) owns 128x64 output; 64 MFMA per K-step per wave.
// PHASE 0: routed H1 (A=xb gathered via ptok, B=w1b, out silu->h1 bf16)  [bid 0..511]
//          + shared GU (A=xb, B=sgub N=2048, out gub bf16)               [bid 512..575]
// PHASE 1: routed Y (A=h1, B=w2b, atomicAdd weighted into out)           [bid 0..511]
//          + shared DOWN (A=act, B=sdnb N=1024, atomicAdd into out)      [bid 512..543]
template <int PHASE>
__global__ __launch_bounds__(512) void gemm256_kernel(
    const bf16* __restrict__ A_sh, const bf16* __restrict__ A_rt,
    const bf16* __restrict__ B_sh, const bf16* __restrict__ B_rt,
    void* __restrict__ O_sh, void* __restrict__ O_rt,
    const int* __restrict__ ptok, const float* __restrict__ pwt,
    const int* __restrict__ offsets) {
  __shared__ bf16 Ash[2][256][64];   // 64 KiB
  __shared__ bf16 Bsh[2][256][64];   // 64 KiB

  const int tid = threadIdx.x;
  const int lane = tid & 63;
  const int wave = tid >> 6;
  const int wm = wave >> 2, wn = wave & 3;

  const bool routed = (int)blockIdx.x < 512;
  int mt, nt, seg = 0, count;
  const bf16* Abase;
  const bf16* Bbase;   // panel base (row 0 of this block's N-tile)
  size_t ostride;      // phase-0 output row stride
  if (routed) {
    int bid = blockIdx.x;
    int e = bid & 15;
    int r = bid >> 4;            // 0..31
    nt = r & 3; mt = r >> 2;     // mt 0..7 (covers count up to 2048)
    seg = offsets[e];
    count = offsets[e + 1] - seg;
    if (mt * 256 >= count) return;
    Abase = A_rt;
    Bbase = B_rt + ((size_t)e << 20) + (size_t)(nt * 256) * KD;
    ostride = 1024;
  } else {
    int sb = blockIdx.x - 512;
    if (PHASE == 0) { mt = sb >> 3; nt = sb & 7; ostride = 2048; }
    else            { mt = sb >> 2; nt = sb & 3; ostride = 1024; }
    count = 1 << 30;
    Abase = A_sh;
    Bbase = B_sh + (size_t)(nt * 256) * KD;
  }

  // staging pointers: 4 A-chunks + 4 B-chunks per thread; chunk c = i*8+wave
  // covers tile rows c*8 + (lane>>3); 16 B per lane per issue
  const bf16* aptr[4];
  const bf16* bptr[4];
#pragma unroll
  for (int i = 0; i < 4; ++i) {
    const int c = i * 8 + wave;
    const int ar = c * 8 + (lane >> 3);         // tile row 0..255
    int grow;
    if (routed) {
      int slot = seg + mt * 256 + ar;
      if (slot > NPAIR - 1) slot = NPAIR - 1;
      grow = (PHASE == 0) ? ptok[slot] : slot;
    } else {
      grow = mt * 256 + ar;
    }
    aptr[i] = Abase + (size_t)grow * KD + (lane & 7) * 8;
    bptr[i] = Bbase + (size_t)ar * KD + (lane & 7) * 8;
  }

  f4acc acc[8][4];
#pragma unroll
  for (int i = 0; i < 8; ++i)
#pragma unroll
    for (int j = 0; j < 4; ++j) acc[i][j] = (f4acc)(0.f);

  auto STAGE = [&](int buf, int kt) {
    const int koff = kt * 64;
#pragma unroll
    for (int i = 0; i < 4; ++i) {
      const int c = i * 8 + wave;
      async16(aptr[i] + koff, (void*)((char*)&Ash[buf][0][0] + c * 1024));
      async16(bptr[i] + koff, (void*)((char*)&Bsh[buf][0][0] + c * 1024));
    }
  };

  STAGE(0, 0);
  __syncthreads();

  for (int kt = 0; kt < 16; ++kt) {
    const int buf = kt & 1;
    if (kt < 15) STAGE(buf ^ 1, kt + 1);   // issue next tile BEFORE compute

#pragma unroll
    for (int ks = 0; ks < 2; ++ks) {
      sh8 fa[8], fb[4];
#pragma unroll
      for (int mi = 0; mi < 8; ++mi)
        fa[mi] = *(const sh8*)&Ash[buf][wm * 128 + mi * 16 + (lane & 15)][ks * 32 + (lane >> 4) * 8];
#pragma unroll
      for (int ni = 0; ni < 4; ++ni)
        fb[ni] = *(const sh8*)&Bsh[buf][wn * 64 + ni * 16 + (lane & 15)][ks * 32 + (lane >> 4) * 8];
#pragma unroll
      for (int mi = 0; mi < 8; ++mi)
#pragma unroll
        for (int ni = 0; ni < 4; ++ni)
          acc[mi][ni] = __builtin_amdgcn_mfma_f32_16x16x32_bf16(fa[mi], fb[ni], acc[mi][ni], 0, 0, 0);
    }
    __syncthreads();   // drains stage (vmcnt) + ds_reads; one barrier per K-step
  }

  // epilogue: C/D col = lane&15 (in ni block), row = (lane>>4)*4+j (in mi block)
  const int cbase = nt * 256 + wn * 64;
  if (PHASE == 0) {
#pragma unroll
    for (int mi = 0; mi < 8; ++mi) {
#pragma unroll
      for (int j = 0; j < 4; ++j) {
        const int tr = wm * 128 + mi * 16 + (lane >> 4) * 4 + j;
        if (routed && mt * 256 + tr >= count) continue;
        short* orow;
        if (routed) orow = (short*)O_rt + (size_t)(seg + mt * 256 + tr) * 1024;
        else        orow = (short*)O_sh + (size_t)(mt * 256 + tr) * ostride;
#pragma unroll
        for (int ni = 0; ni < 4; ++ni) {
          const int cloc = cbase + ni * 16 + (lane & 15);
          float v = acc[mi][ni][j];
          if (routed) v = v / (1.f + expf(-v));   // silu fused into H1
          orow[cloc] = f2bf(v);
        }
      }
    }
  } else {
#pragma unroll
    for (int mi = 0; mi < 8; ++mi) {
#pragma unroll
      for (int j = 0; j < 4; ++j) {
        const int tr = wm * 128 + mi * 16 + (lane >> 4) * 4 + j;
        if (routed && mt * 256 + tr >= count) continue;
        float w = 1.f;
        float* orow;
        if (routed) {
          const int slot = seg + mt * 256 + tr;
          orow = (float*)O_rt + (size_t)ptok[slot] * 1024;
          w = pwt[slot];
        } else {
          orow = (float*)O_sh + (size_t)(mt * 256 + tr) * 1024;
        }
#pragma unroll
        for (int ni = 0; ni < 4; ++ni) {
          const int cloc = cbase + ni * 16 + (lane & 15);
          unsafeAtomicAdd(orow + cloc, w * acc[mi][ni][j]);
        }
      }
    }
  }
}

extern "C" void kernel_launch(void* const* d_in, const int* in_sizes, int n_in,
                              void* d_out, int out_size, void* d_ws, size_t ws_size,
                              hipStream_t stream) {
  const float* x   = (const float*)d_in[0];
  const float* gw  = (const float*)d_in[1];
  const float* w1  = (const float*)d_in[2];
  const float* w2  = (const float*)d_in[3];
  const float* sgu = (const float*)d_in[4];
  const float* sdn = (const float*)d_in[5];
  float* out = (float*)d_out;

  char* ws = (char*)d_ws;
  bf16*  xb    = (bf16*)(ws + OFF_XB);
  bf16*  gub   = (bf16*)(ws + OFF_GUB);
  bf16*  act   = (bf16*)(ws + OFF_ACT);
  bf16*  h1    = (bf16*)(ws + OFF_H1);
  bf16*  w1b   = (bf16*)(ws + OFF_W1B);   // aliased as w2b after K2
  bf16*  sgub  = (bf16*)(ws + OFF_SGUB);
  bf16*  sdnb  = (bf16*)(ws + OFF_SDNB);
  int*   topi  = (int*)(ws + OFF_TOPI);
  float* topv  = (float*)(ws + OFF_TOPV);
  int*   ptok  = (int*)(ws + OFF_PTOK);
  float* pwt   = (float*)(ws + OFF_PWT);
  int*   offs  = (int*)(ws + OFF_OFFS);

  hipMemsetAsync(d_out, 0, (size_t)out_size * sizeof(float), stream);

  router_kernel<<<512, 256, 0, stream>>>(x, gw, topi, topv, (short*)xb);
  route_build_kernel<<<1, 1024, 0, stream>>>(topi, topv, offs, ptok, pwt);
  cast1_kernel<<<19456, 256, 0, stream>>>(w1, sgu, sdn,
                                          (short*)w1b, (short*)sgub, (short*)sdnb);

  // K2: routed H1 (0..511) + shared GU (512..575)
  gemm256_kernel<0><<<576, 512, 0, stream>>>(xb, xb, sgub, w1b,
                                             gub, h1, ptok, pwt, offs);
  // w2 cast (0..16383) + act (16384..18431); w2b aliases w1b
  act_w2_kernel<<<18432, 256, 0, stream>>>(w2, (short*)w1b, (const short*)gub, (short*)act);

  // K3: routed Y (0..511) + shared DOWN (512..543); atomicAdd into out
  gemm256_kernel<1><<<544, 512, 0, stream>>>(act, h1, sdnb, w1b /*w2b*/,
                                             out, out, ptok, pwt, offs);
}

// Round 10
// 165.248 us; speedup vs baseline: 1.3823x; 1.3823x over previous
//
#include <hip/hip_runtime.h>
#include <hip/hip_bf16.h>
#include <math.h>

using bf16 = __hip_bfloat16;

typedef __attribute__((ext_vector_type(4))) float fv4;
typedef __attribute__((ext_vector_type(4))) short sh4;
typedef __attribute__((ext_vector_type(8))) short sh8;
typedef __attribute__((ext_vector_type(4))) float f4acc;

#define T_TOK 2048
#define HD    1024
#define NE    16
#define KD    1024
#define NPAIR 8192

// ---- workspace layout (bytes); peak ~34 MB ----
static constexpr size_t OFF_XB    = 0;          // bf16 xb  [2048][1024]  4 MiB
static constexpr size_t OFF_GUB   = 4194304;    // bf16 gu  [2048][2048]  8 MiB
static constexpr size_t OFF_ACT   = 12582912;   // bf16 act [2048][1024]  4 MiB
static constexpr size_t OFF_H1    = 16777216;   // bf16 h1  [8192][1024] 16 MiB
static constexpr size_t OFF_TOPI  = 33554432;   // int  [8192]
static constexpr size_t OFF_TOPV  = 33587200;   // f32  [8192]
static constexpr size_t OFF_PTOK  = 33619968;   // int  [8192]
static constexpr size_t OFF_PWT   = 33652736;   // f32  [8192]
static constexpr size_t OFF_OFFS  = 33685504;   // int  [17]
static constexpr size_t OFF_CNT   = 33686016;   // int  [8][16]
static constexpr size_t OFF_CBASE = 33686528;   // int  [8][16]

__device__ __forceinline__ short f2bf(float f) {
  __hip_bfloat16 h = __float2bfloat16(f);
  union { __hip_bfloat16 b; short s; } u; u.b = h; return u.s;
}
__device__ __forceinline__ float bf2f(short s) {
  union { unsigned u; float f; } c; c.u = ((unsigned)(unsigned short)s) << 16; return c.f;
}
__device__ __forceinline__ void async16(const void* g, void* l) {
  __builtin_amdgcn_global_load_lds(
      (const __attribute__((address_space(1))) void*)g,
      (__attribute__((address_space(3))) void*)l, 16, 0, 0);
}

// ---------- router: logits+top4 (no atomics), emits xb bf16, zeroes d_out ----------
__global__ __launch_bounds__(256) void router_kernel(const float* __restrict__ x,
                                                     const float* __restrict__ gw,
                                                     int* __restrict__ topi,
                                                     float* __restrict__ topv,
                                                     short* __restrict__ xb,
                                                     float* __restrict__ out) {
  __shared__ float gsh[NE * HD];  // 64 KiB
  const int tid = threadIdx.x;
  const int wave = tid >> 6;
  const int lane = tid & 63;
  const int t = blockIdx.x * 4 + wave;

#pragma unroll
  for (int r = 0; r < 16; ++r) {
    int idx = r * 256 + tid;
    ((fv4*)gsh)[idx] = ((const fv4*)gw)[idx];
  }

  const float* xr = x + (size_t)t * HD;
  fv4 xa[4];
#pragma unroll
  for (int q = 0; q < 4; ++q) xa[q] = *(const fv4*)(xr + q * 256 + lane * 4);

  // by-products: bf16 x row + zero the output row (out untouched until K3)
#pragma unroll
  for (int q = 0; q < 4; ++q) {
    sh4 o; o[0]=f2bf(xa[q][0]); o[1]=f2bf(xa[q][1]); o[2]=f2bf(xa[q][2]); o[3]=f2bf(xa[q][3]);
    *(sh4*)(xb + (size_t)t * HD + q * 256 + lane * 4) = o;
    *(fv4*)(out + (size_t)t * HD + q * 256 + lane * 4) = (fv4)(0.f);
  }

  __syncthreads();

  float p[NE];
#pragma unroll
  for (int e = 0; e < NE; ++e) {
    const float* g = gsh + e * HD;
    float a = 0.f;
#pragma unroll
    for (int q = 0; q < 4; ++q) {
      fv4 gv = *(const fv4*)(g + q * 256 + lane * 4);
      a += xa[q][0] * gv[0] + xa[q][1] * gv[1] + xa[q][2] * gv[2] + xa[q][3] * gv[3];
    }
    p[e] = a;
  }
#pragma unroll
  for (int off = 1; off < 64; off <<= 1) {
#pragma unroll
    for (int e = 0; e < NE; ++e) p[e] += __shfl_xor(p[e], off);
  }

  int sel_i[4]; float sel_v[4];
#pragma unroll
  for (int k = 0; k < 4; ++k) {
    float best = p[0]; int bi = 0;
#pragma unroll
    for (int e = 1; e < NE; ++e) {
      bool c = p[e] > best;
      best = c ? p[e] : best;
      bi   = c ? e : bi;
    }
    sel_i[k] = bi; sel_v[k] = best;
#pragma unroll
    for (int e = 0; e < NE; ++e) p[e] = (e == bi) ? -3.4e38f : p[e];
  }
  float m = sel_v[0];
  float e0 = expf(sel_v[0] - m), e1 = expf(sel_v[1] - m);
  float e2 = expf(sel_v[2] - m), e3 = expf(sel_v[3] - m);
  float inv = 1.f / (e0 + e1 + e2 + e3);

  if (lane == 0) {
    topi[t * 4 + 0] = sel_i[0]; topv[t * 4 + 0] = e0 * inv;
    topi[t * 4 + 1] = sel_i[1]; topv[t * 4 + 1] = e1 * inv;
    topi[t * 4 + 2] = sel_i[2]; topv[t * 4 + 2] = e2 * inv;
    topi[t * 4 + 3] = sel_i[3]; topv[t * 4 + 3] = e3 * inv;
  }
}

// ---------- parallel route build: count (8 blk) -> scan (1) -> compact (8 blk) ----------
__global__ __launch_bounds__(1024) void count_kernel(const int* __restrict__ topi,
                                                     int* __restrict__ cnt) {
  const int b = blockIdx.x;            // chunk of 1024 pairs
  const int wave = threadIdx.x >> 6;   // == expert
  const int lane = threadIdx.x & 63;
  const int base = b * 1024;
  int c = 0;
#pragma unroll
  for (int i = 0; i < 16; ++i) {
    unsigned long long m = __ballot(topi[base + i * 64 + lane] == wave);
    c += __popcll(m);
  }
  if (lane == 0) cnt[b * NE + wave] = c;
}

__global__ void scan2_kernel(const int* __restrict__ cnt,
                             int* __restrict__ offsets,
                             int* __restrict__ cbase) {
  if (threadIdx.x == 0 && blockIdx.x == 0) {
    int acc = 0;
    for (int e = 0; e < NE; ++e) {
      offsets[e] = acc;
      for (int b = 0; b < 8; ++b) { cbase[b * NE + e] = acc; acc += cnt[b * NE + e]; }
    }
    offsets[NE] = acc;
  }
}

__global__ __launch_bounds__(1024) void compact_kernel(const int* __restrict__ topi,
                                                       const float* __restrict__ topv,
                                                       const int* __restrict__ cbase,
                                                       int* __restrict__ ptok,
                                                       float* __restrict__ pwt) {
  const int b = blockIdx.x;
  const int wave = threadIdx.x >> 6;   // == expert
  const int lane = threadIdx.x & 63;
  const int base = b * 1024;
  int slot = cbase[b * NE + wave];
#pragma unroll
  for (int i = 0; i < 16; ++i) {
    const int p = base + i * 64 + lane;
    const bool match = (topi[p] == wave);
    unsigned long long m = __ballot(match);
    unsigned long long lt = (lane == 0) ? 0ull : ((~0ull) >> (64 - lane));
    int pre = __popcll(m & lt);
    if (match) { ptok[slot + pre] = p >> 2; pwt[slot + pre] = topv[p]; }
    slot += __popcll(m);
  }
}

// ---------- shared-expert activation: act = silu(gate) * up (bf16 in/out) ----------
__global__ __launch_bounds__(256) void act_kernel(const short* __restrict__ gub,
                                                  short* __restrict__ act) {
  int i = blockIdx.x * 256 + threadIdx.x;
  int t = i >> 8, g = i & 255;
  sh4 gs = *(const sh4*)(gub + (size_t)t * 2048 + g * 4);
  sh4 us = *(const sh4*)(gub + (size_t)t * 2048 + 1024 + g * 4);
  sh4 o;
#pragma unroll
  for (int q = 0; q < 4; ++q) {
    float gg = bf2f(gs[q]);
    float s = gg / (1.f + expf(-gg)) * bf2f(us[q]);
    o[q] = f2bf(s);
  }
  *(sh4*)(act + (size_t)t * 1024 + g * 4) = o;
}

// ---------- paired GEMM: R4's proven plain 2-phase body, 128x128, BK=32 ----------
// A bf16 via async16 (dbuf), B fp32 reg-staged -> cvt -> ds_write (dbuf).
// One __syncthreads per K-step; no asm waits, no swizzles (R4 measured 291-437 TF).
// PHASE 0: routed H1 (A=xb gathered, B=w1, silu->h1 bf16)     [bid 0..2047]
//          + shared GU (A=xb, B=sgu N=2048, gub bf16)          [bid 2048..2303]
// PHASE 1: routed Y (A=h1, B=w2, atomicAdd weighted into out)  [bid 0..2047]
//          + shared DOWN (A=act, B=sdn, atomicAdd into out)    [bid 2048..2175]
template <int PHASE>
__global__ __launch_bounds__(256) void gemm_pair_kernel(
    const bf16* __restrict__ A_sh, const bf16* __restrict__ A_rt,
    const float* __restrict__ B_sh, const float* __restrict__ B_rt,
    void* __restrict__ O_sh, void* __restrict__ O_rt,
    const int* __restrict__ ptok, const float* __restrict__ pwt,
    const int* __restrict__ offsets) {
  __shared__ bf16 Ash[2][128][32];
  __shared__ bf16 Bsh[2][128][32];

  const int tid = threadIdx.x;
  const int lane = tid & 63;
  const int wave = tid >> 6;
  const int wm = wave >> 1, wn = wave & 1;

  const bool routed = (int)blockIdx.x < 2048;
  int mt, nt, seg_start = 0, count = 0;
  const bf16* Abase;
  const float* Bpanel;
  if (routed) {
    int bid = blockIdx.x;
    int e = bid & 15;            // expert -> XCD e%8 (w[e] L2 locality)
    int r = bid >> 4;
    mt = r >> 3; nt = r & 7;
    seg_start = offsets[e];
    count = offsets[e + 1] - seg_start;
    if (mt * 128 >= count) return;
    Abase = A_rt;
    Bpanel = B_rt + ((size_t)e << 20) + (size_t)(nt * 128) * KD;
  } else {
    int sb = blockIdx.x - 2048;
    constexpr int nwg = (PHASE == 0) ? 256 : 128;
    constexpr int cpx = nwg >> 3;
    int sw = (sb & 7) * cpx + (sb >> 3);
    nt = sw >> 4; mt = sw & 15;
    count = 1 << 30;
    Abase = A_sh;
    Bpanel = B_sh + (size_t)(nt * 128) * KD;
  }

  // A row pointers (2 async16 per wave per K-step)
  const bf16* arow[2];
#pragma unroll
  for (int r = 0; r < 2; ++r) {
    int rowloc = r * 64 + wave * 16 + (lane >> 2);
    int grow;
    if (routed) {
      int slot = seg_start + mt * 128 + rowloc;
      if (slot > NPAIR - 1) slot = NPAIR - 1;
      grow = (PHASE == 0) ? ptok[slot] : slot;
    } else {
      grow = mt * 128 + rowloc;
    }
    arow[r] = Abase + (size_t)grow * KD + (lane & 3) * 8;
  }

  // B row pointers (4 fv4/thread per K-step) + LDS write coords
  const float* brow[4];
  int bwrow[4], bwcol[4];
#pragma unroll
  for (int r = 0; r < 4; ++r) {
    int idx = (r << 8) + tid;
    int row = idx >> 3, cg = idx & 7;
    brow[r] = Bpanel + (size_t)row * KD + (cg << 2);
    bwrow[r] = row; bwcol[r] = cg << 2;
  }

  f4acc acc[4][4];
#pragma unroll
  for (int i = 0; i < 4; ++i)
#pragma unroll
    for (int j = 0; j < 4; ++j) acc[i][j] = (f4acc)(0.f);

  // ---- prologue: stage kt=0 into buf 0 ----
  {
    fv4 b0 = *(const fv4*)(brow[0]);
    fv4 b1 = *(const fv4*)(brow[1]);
    fv4 b2 = *(const fv4*)(brow[2]);
    fv4 b3 = *(const fv4*)(brow[3]);
    async16(arow[0], (void*)&Ash[0][wave * 16][0]);
    async16(arow[1], (void*)&Ash[0][64 + wave * 16][0]);
    sh4 p0; p0[0]=f2bf(b0[0]); p0[1]=f2bf(b0[1]); p0[2]=f2bf(b0[2]); p0[3]=f2bf(b0[3]);
    sh4 p1; p1[0]=f2bf(b1[0]); p1[1]=f2bf(b1[1]); p1[2]=f2bf(b1[2]); p1[3]=f2bf(b1[3]);
    sh4 p2; p2[0]=f2bf(b2[0]); p2[1]=f2bf(b2[1]); p2[2]=f2bf(b2[2]); p2[3]=f2bf(b2[3]);
    sh4 p3; p3[0]=f2bf(b3[0]); p3[1]=f2bf(b3[1]); p3[2]=f2bf(b3[2]); p3[3]=f2bf(b3[3]);
    *(sh4*)&Bsh[0][bwrow[0]][bwcol[0]] = p0;
    *(sh4*)&Bsh[0][bwrow[1]][bwcol[1]] = p1;
    *(sh4*)&Bsh[0][bwrow[2]][bwcol[2]] = p2;
    *(sh4*)&Bsh[0][bwrow[3]][bwcol[3]] = p3;
  }
  __syncthreads();

  int buf = 0;
  for (int kt = 0; kt < 32; ++kt) {
    const int k0n = (kt + 1) * 32;
    const bool has_next = (kt < 31);
    fv4 n0, n1, n2, n3;
    if (has_next) {
      async16(arow[0] + k0n, (void*)&Ash[buf ^ 1][wave * 16][0]);
      async16(arow[1] + k0n, (void*)&Ash[buf ^ 1][64 + wave * 16][0]);
      n0 = *(const fv4*)(brow[0] + k0n);
      n1 = *(const fv4*)(brow[1] + k0n);
      n2 = *(const fv4*)(brow[2] + k0n);
      n3 = *(const fv4*)(brow[3] + k0n);
    }

    sh8 fa[4], fb[4];
#pragma unroll
    for (int mi = 0; mi < 4; ++mi)
      fa[mi] = *(const sh8*)&Ash[buf][wm * 64 + mi * 16 + (lane & 15)][(lane >> 4) * 8];
#pragma unroll
    for (int ni = 0; ni < 4; ++ni)
      fb[ni] = *(const sh8*)&Bsh[buf][wn * 64 + ni * 16 + (lane & 15)][(lane >> 4) * 8];
#pragma unroll
    for (int mi = 0; mi < 4; ++mi)
#pragma unroll
      for (int ni = 0; ni < 4; ++ni)
        acc[mi][ni] = __builtin_amdgcn_mfma_f32_16x16x32_bf16(fa[mi], fb[ni], acc[mi][ni], 0, 0, 0);

    if (has_next) {
      sh4 p0; p0[0]=f2bf(n0[0]); p0[1]=f2bf(n0[1]); p0[2]=f2bf(n0[2]); p0[3]=f2bf(n0[3]);
      sh4 p1; p1[0]=f2bf(n1[0]); p1[1]=f2bf(n1[1]); p1[2]=f2bf(n1[2]); p1[3]=f2bf(n1[3]);
      sh4 p2; p2[0]=f2bf(n2[0]); p2[1]=f2bf(n2[1]); p2[2]=f2bf(n2[2]); p2[3]=f2bf(n2[3]);
      sh4 p3; p3[0]=f2bf(n3[0]); p3[1]=f2bf(n3[1]); p3[2]=f2bf(n3[2]); p3[3]=f2bf(n3[3]);
      *(sh4*)&Bsh[buf ^ 1][bwrow[0]][bwcol[0]] = p0;
      *(sh4*)&Bsh[buf ^ 1][bwrow[1]][bwcol[1]] = p1;
      *(sh4*)&Bsh[buf ^ 1][bwrow[2]][bwcol[2]] = p2;
      *(sh4*)&Bsh[buf ^ 1][bwrow[3]][bwcol[3]] = p3;
    }
    __syncthreads();
    buf ^= 1;
  }

  // epilogue: C/D layout col = lane&15, row = (lane>>4)*4 + j
  if (PHASE == 0) {
    if (routed) {
#pragma unroll
      for (int mi = 0; mi < 4; ++mi) {
#pragma unroll
        for (int j = 0; j < 4; ++j) {
          int rloc = wm * 64 + mi * 16 + (lane >> 4) * 4 + j;
          if (mt * 128 + rloc >= count) continue;
          size_t orow = (size_t)(seg_start + mt * 128 + rloc) * 1024 + nt * 128;
#pragma unroll
          for (int ni = 0; ni < 4; ++ni) {
            int cloc = wn * 64 + ni * 16 + (lane & 15);
            float v = acc[mi][ni][j];
            float s = v / (1.f + expf(-v));
            ((short*)O_rt)[orow + cloc] = f2bf(s);
          }
        }
      }
    } else {
#pragma unroll
      for (int mi = 0; mi < 4; ++mi) {
#pragma unroll
        for (int j = 0; j < 4; ++j) {
          int rloc = wm * 64 + mi * 16 + (lane >> 4) * 4 + j;
          size_t orow = (size_t)(mt * 128 + rloc) * 2048 + nt * 128;
#pragma unroll
          for (int ni = 0; ni < 4; ++ni) {
            int cloc = wn * 64 + ni * 16 + (lane & 15);
            ((short*)O_sh)[orow + cloc] = f2bf(acc[mi][ni][j]);
          }
        }
      }
    }
  } else {
    if (routed) {
#pragma unroll
      for (int mi = 0; mi < 4; ++mi) {
#pragma unroll
        for (int j = 0; j < 4; ++j) {
          int rloc = wm * 64 + mi * 16 + (lane >> 4) * 4 + j;
          if (mt * 128 + rloc >= count) continue;
          int slot = seg_start + mt * 128 + rloc;
          int token = ptok[slot];
          float w = pwt[slot];
          float* orow = (float*)O_rt + (size_t)token * 1024 + nt * 128;
#pragma unroll
          for (int ni = 0; ni < 4; ++ni) {
            int cloc = wn * 64 + ni * 16 + (lane & 15);
            unsafeAtomicAdd(orow + cloc, w * acc[mi][ni][j]);
          }
        }
      }
    } else {
#pragma unroll
      for (int mi = 0; mi < 4; ++mi) {
#pragma unroll
        for (int j = 0; j < 4; ++j) {
          int rloc = wm * 64 + mi * 16 + (lane >> 4) * 4 + j;
          float* orow = (float*)O_sh + (size_t)(mt * 128 + rloc) * 1024 + nt * 128;
#pragma unroll
          for (int ni = 0; ni < 4; ++ni) {
            int cloc = wn * 64 + ni * 16 + (lane & 15);
            unsafeAtomicAdd(orow + cloc, acc[mi][ni][j]);
          }
        }
      }
    }
  }
}

extern "C" void kernel_launch(void* const* d_in, const int* in_sizes, int n_in,
                              void* d_out, int out_size, void* d_ws, size_t ws_size,
                              hipStream_t stream) {
  const float* x   = (const float*)d_in[0];
  const float* gw  = (const float*)d_in[1];
  const float* w1  = (const float*)d_in[2];
  const float* w2  = (const float*)d_in[3];
  const float* sgu = (const float*)d_in[4];
  const float* sdn = (const float*)d_in[5];
  float* out = (float*)d_out;

  char* ws = (char*)d_ws;
  bf16*  xb    = (bf16*)(ws + OFF_XB);
  bf16*  gub   = (bf16*)(ws + OFF_GUB);
  bf16*  act   = (bf16*)(ws + OFF_ACT);
  bf16*  h1    = (bf16*)(ws + OFF_H1);
  int*   topi  = (int*)(ws + OFF_TOPI);
  float* topv  = (float*)(ws + OFF_TOPV);
  int*   ptok  = (int*)(ws + OFF_PTOK);
  float* pwt   = (float*)(ws + OFF_PWT);
  int*   offs  = (int*)(ws + OFF_OFFS);
  int*   cnt   = (int*)(ws + OFF_CNT);
  int*   cbase = (int*)(ws + OFF_CBASE);

  // router also casts x->bf16 and zeroes d_out (no separate memset/cast launches)
  router_kernel<<<512, 256, 0, stream>>>(x, gw, topi, topv, (short*)xb, out);
  count_kernel<<<8, 1024, 0, stream>>>(topi, cnt);
  scan2_kernel<<<1, 64, 0, stream>>>(cnt, offs, cbase);
  compact_kernel<<<8, 1024, 0, stream>>>(topi, topv, cbase, ptok, pwt);

  // K2: routed H1 (0..2047) + shared GU (2048..2303)
  gemm_pair_kernel<0><<<2304, 256, 0, stream>>>(xb, xb, sgu, w1,
                                                gub, h1, ptok, pwt, offs);
  act_kernel<<<2048, 256, 0, stream>>>((const short*)gub, (short*)act);

  // K3: routed Y (0..2047) + shared DOWN (2048..2175); atomicAdd into out
  gemm_pair_kernel<1><<<2176, 256, 0, stream>>>(act, h1, sdn, w2,
                                                out, out, ptok, pwt, offs);
}